// Round 1
// baseline (165.688 us; speedup 1.0000x reference)
//
#include <hip/hip_runtime.h>

// Problem constants (B,N,F,K) = (4096, 2048, 64, 64)
#define NB 4096
#define NN 2048
#define NF 64
#define NK 64

// ws layout (floats):
//   VT    [64*2048]  = 131072   : V^T, VT[k*NN + i] = vector[i, f2f[i], k]
//   vnorm [2048]                : ||V_i||^2
//   lin   [4096]                : per-row linear part
//   srow  [4096]                : per-row  sum_k T[b,k]^2 - sum_i vnorm[i] X[b,i]^2
// total ~565 KB

// ---------------- Kernel 1: gather V^T and vnorm ----------------
__global__ __launch_bounds__(256) void k_gather(const float* __restrict__ vec,
                                                const int* __restrict__ f2f,
                                                float* __restrict__ VT,
                                                float* __restrict__ vnorm) {
    int gwave = (blockIdx.x * 256 + threadIdx.x) >> 6;  // one feature row per wave
    int lane  = threadIdx.x & 63;                        // lane = k
    if (gwave >= NN) return;
    int i = gwave;
    int f = f2f[i];
    float v = vec[(size_t)i * (NF * NK) + (size_t)f * NK + lane];
    VT[(size_t)lane * NN + i] = v;  // scattered 4B stores, tiny total (512KB)
    float sq = v * v;
    #pragma unroll
    for (int m = 32; m; m >>= 1) sq += __shfl_xor(sq, m, 64);
    if (lane == 0) vnorm[i] = sq;
}

// ---------------- Kernel 2: fused skinny GEMM + per-row reductions ----------------
// Block: 256 threads (4 waves), 16 batch rows per block, full K=64 (lane = k).
// Wave w owns rows [4w, 4w+4); loops over all i in tiles of 128.
#define TI 128
#define VS_STRIDE 132   // 128 + 4 pad: keeps 16B alignment, even bank spread for b128

__global__ __launch_bounds__(256) void k_main(const float* __restrict__ X,
                                              const float* __restrict__ Wg,
                                              const float* __restrict__ VT,
                                              const float* __restrict__ vnormg,
                                              float* __restrict__ lin_ws,
                                              float* __restrict__ s_ws) {
    __shared__ float Xs[16 * TI];          // 8 KB
    __shared__ float Vs[64 * VS_STRIDE];   // 33 KB
    __shared__ float Ws[TI];
    __shared__ float vns[TI];

    const int t     = threadIdx.x;
    const int wave  = t >> 6;
    const int lane  = t & 63;          // lane = k
    const int rbase = wave * 4;        // 4 rows per wave
    const int b0    = blockIdx.x * 16;

    float acc[4] = {0.f, 0.f, 0.f, 0.f};   // T[b0+rbase+r, lane]
    float lin[4] = {0.f, 0.f, 0.f, 0.f};   // lane-partial linear
    float dd [4] = {0.f, 0.f, 0.f, 0.f};   // lane-partial diag term

    // staging index precompute
    const int xr  = t >> 4;        // 0..15 row
    const int xci = t & 15;        // float4 col index
    const int vk  = t >> 2;        // 0..63 k-row
    const int vci = t & 3;         // base float4 col

    for (int tile = 0; tile < NN / TI; ++tile) {
        const int i0 = tile * TI;
        __syncthreads();  // protect previous tile's LDS from overwrite

        // stage X tile: rows b0..b0+15, cols i0..i0+127
        {
            const float4* xrow = reinterpret_cast<const float4*>(X + (size_t)(b0 + xr) * NN + i0);
            *reinterpret_cast<float4*>(&Xs[xr * TI + 4 * xci])        = xrow[xci];
            *reinterpret_cast<float4*>(&Xs[xr * TI + 4 * (xci + 16)]) = xrow[xci + 16];
        }
        // stage V^T tile: k rows 0..63, cols i0..i0+127 (8 float4 per thread)
        {
            const float4* vrow = reinterpret_cast<const float4*>(VT + (size_t)vk * NN + i0);
            #pragma unroll
            for (int j = 0; j < 8; ++j) {
                int c4 = vci + 4 * j;
                *reinterpret_cast<float4*>(&Vs[vk * VS_STRIDE + 4 * c4]) = vrow[c4];
            }
        }
        // stage W and vnorm slices
        if (t < TI)            Ws[t]        = Wg[i0 + t];
        else                   vns[t - TI]  = vnormg[i0 + (t - TI)];
        __syncthreads();

        // ---- linear / diag phase: lanes parallel over ii (2 per lane) ----
        {
            float w1 = Ws[lane], w2 = Ws[lane + 64];
            float n1 = vns[lane], n2 = vns[lane + 64];
            #pragma unroll
            for (int r = 0; r < 4; ++r) {
                float x1 = Xs[(rbase + r) * TI + lane];
                float x2 = Xs[(rbase + r) * TI + lane + 64];
                lin[r] += x1 * w1 + x2 * w2;
                dd[r]  += x1 * x1 * n1 + x2 * x2 * n2;
            }
        }

        // ---- T phase: acc[r] += sum_ii Xs[row][ii] * Vs[lane][ii] ----
        #pragma unroll 4
        for (int ii = 0; ii < TI; ii += 4) {
            float4 v = *reinterpret_cast<const float4*>(&Vs[lane * VS_STRIDE + ii]);
            #pragma unroll
            for (int r = 0; r < 4; ++r) {
                float4 x = *reinterpret_cast<const float4*>(&Xs[(rbase + r) * TI + ii]);
                acc[r] = fmaf(v.x, x.x, acc[r]);
                acc[r] = fmaf(v.y, x.y, acc[r]);
                acc[r] = fmaf(v.z, x.z, acc[r]);
                acc[r] = fmaf(v.w, x.w, acc[r]);
            }
        }
    }

    // ---- epilogue: wave-level reductions, one write per row ----
    #pragma unroll
    for (int r = 0; r < 4; ++r) {
        float t2 = acc[r] * acc[r];   // T^2, to be summed over k (lanes)
        float lr = lin[r];
        float dr = dd[r];
        #pragma unroll
        for (int m = 32; m; m >>= 1) {
            t2 += __shfl_xor(t2, m, 64);
            lr += __shfl_xor(lr, m, 64);
            dr += __shfl_xor(dr, m, 64);
        }
        if (lane == 0) {
            int b = b0 + rbase + r;
            lin_ws[b] = lr;
            s_ws[b]   = t2 - dr;
        }
    }
}

// ---------------- Kernel 3: fp64 reduce + finalize ----------------
__global__ __launch_bounds__(256) void k_final(const float* __restrict__ lin_ws,
                                               const float* __restrict__ s_ws,
                                               const float* __restrict__ bptr,
                                               float* __restrict__ out) {
    __shared__ double red[256];
    int t = threadIdx.x;
    double a = 0.0;
    for (int j = t; j < NB; j += 256) a += (double)s_ws[j];
    red[t] = a;
    __syncthreads();
    #pragma unroll
    for (int s = 128; s; s >>= 1) {
        if (t < s) red[t] += red[t + s];
        __syncthreads();
    }
    float inter = (float)(0.5 * red[0]);
    float bias  = bptr[0];
    for (int j = t; j < NB; j += 256) out[j] = lin_ws[j] + bias + inter;
}

extern "C" void kernel_launch(void* const* d_in, const int* in_sizes, int n_in,
                              void* d_out, int out_size, void* d_ws, size_t ws_size,
                              hipStream_t stream) {
    const float* X    = (const float*)d_in[0];
    const float* W    = (const float*)d_in[1];
    const float* bias = (const float*)d_in[2];
    const float* vec  = (const float*)d_in[3];
    const int*   f2f  = (const int*)d_in[4];
    float* out = (float*)d_out;

    float* ws    = (float*)d_ws;
    float* VT    = ws;                    // 131072 floats
    float* vnorm = VT + NF * NN;          // 2048
    float* lin   = vnorm + NN;            // 4096
    float* srow  = lin + NB;              // 4096

    // k1: 2048 feature rows, one wave each -> 2048 waves = 512 blocks x 256
    k_gather<<<512, 256, 0, stream>>>(vec, f2f, VT, vnorm);
    // k2: 4096 batch rows / 16 per block = 256 blocks
    k_main<<<256, 256, 0, stream>>>(X, W, VT, vnorm, lin, srow);
    // k3: single block finalize
    k_final<<<1, 256, 0, stream>>>(lin, srow, bias, out);
}

// Round 2
// 136.360 us; speedup vs baseline: 1.2151x; 1.2151x over previous
//
#include <hip/hip_runtime.h>

// (B,N,F,K) = (4096, 2048, 64, 64)
#define NB 4096
#define NN 2048
#define NF 64
#define NK 64
#define NCHUNK 32          // i-chunks of 64
#define NRG 16             // row-groups of 256

// ws layout (floats):
//   Vg    [2048*64]  : gathered V rows, Vg[i*64+k] = vector[i, f2f[i], k]
//   vnorm [2048]
//   lin   [4096]     (atomic-accumulated, memset 0 first)
//   dd    [4096]     (atomic-accumulated, memset 0 first)
//   srow  [4096]
//   T     [32][4096][64] partial path (32 MB)  OR  [4096][64] atomic path (1 MB)
#define WS_VG     0
#define WS_VNORM  (NN * NK)                 // 131072
#define WS_LIN    (WS_VNORM + NN)           // 133120
#define WS_DD     (WS_LIN + NB)             // 137216
#define WS_SROW   (WS_DD + NB)              // 141312
#define WS_T      (WS_SROW + NB)            // 145408

// ---------- k_prep: gather Vg + vnorm (coalesced, one wave per feature) ----------
__global__ __launch_bounds__(256) void k_prep(const float* __restrict__ vec,
                                              const int* __restrict__ f2f,
                                              float* __restrict__ Vg,
                                              float* __restrict__ vnorm) {
    int i    = (blockIdx.x * 256 + threadIdx.x) >> 6;   // feature row
    int lane = threadIdx.x & 63;                        // k
    int f = f2f[i];
    float v = vec[(size_t)i * (NF * NK) + (size_t)f * NK + lane];
    Vg[(size_t)i * NK + lane] = v;                      // 256B coalesced per wave
    float sq = v * v;
    #pragma unroll
    for (int m = 32; m; m >>= 1) sq += __shfl_xor(sq, m, 64);
    if (lane == 0) vnorm[i] = sq;
}

// ---------- k_main: lane=row GEMM chunk, V via scalar loads ----------
// block: 256 threads = rows r0..r0+255, i-chunk of 64. grid = 16 x 32 = 512.
template <bool PART>
__global__ __launch_bounds__(256) void k_main(const float* __restrict__ X,
                                              const float* __restrict__ Wg,
                                              const float* __restrict__ Vg,
                                              const float* __restrict__ vn,
                                              float* __restrict__ Tout,
                                              float* __restrict__ lin_ws,
                                              float* __restrict__ dd_ws) {
    __shared__ float sm[256 * 65];   // 65 KB: staging [i][row] stride 257, epi [row][k] stride 65

    const int t  = threadIdx.x;
    const int rg = blockIdx.x >> 5;         // 0..15
    const int c  = blockIdx.x & 31;         // 0..31
    const int r0 = rg * 256;
    const int i0 = c * 64;

    // ---- stage X[r0..r0+255][i0..i0+63] transposed into sm[i*257 + r] ----
    {
        const int rr = t >> 4;              // 0..15
        const int c4 = (t & 15) * 4;        // 0..60
        #pragma unroll
        for (int m = 0; m < 16; ++m) {
            int r = rr + 16 * m;
            float4 x = *reinterpret_cast<const float4*>(
                X + (size_t)(r0 + r) * NN + i0 + c4);
            sm[(c4 + 0) * 257 + r] = x.x;   // bank = (4c+d+r)%32 -> 2-way (free)
            sm[(c4 + 1) * 257 + r] = x.y;
            sm[(c4 + 2) * 257 + r] = x.z;
            sm[(c4 + 3) * 257 + r] = x.w;
        }
    }

    float acc[NK];
    #pragma unroll
    for (int k = 0; k < NK; ++k) acc[k] = 0.f;
    float lin = 0.f, dd = 0.f;

    const float* __restrict__ vbase = Vg + (size_t)i0 * NK;
    const float* __restrict__ wbase = Wg + i0;
    const float* __restrict__ nbase = vn + i0;

    __syncthreads();

    // ---- inner: 64 i x 64 k. V/W/vn are wave-uniform -> s_load path ----
    #pragma unroll 2
    for (int i = 0; i < 64; ++i) {
        float x  = sm[i * 257 + t];         // bank (i+t)%32 -> 2-way free
        float wv = wbase[i];                // uniform
        float nv = nbase[i];                // uniform
        lin = fmaf(x, wv, lin);
        dd  = fmaf(x * x, nv, dd);
        #pragma unroll
        for (int k = 0; k < NK; ++k)
            acc[k] = fmaf(x, vbase[i * NK + k], acc[k]);
    }

    // ---- epilogue: transpose acc via LDS, coalesced store/atomic ----
    __syncthreads();
    #pragma unroll
    for (int k = 0; k < NK; ++k)
        sm[t * 65 + k] = acc[k];            // bank (t+k)%32 -> 2-way free
    __syncthreads();

    {
        const int rr = t >> 4;
        const int k4 = (t & 15) * 4;
        #pragma unroll
        for (int m = 0; m < 16; ++m) {
            int r = rr + 16 * m;
            float4 v;
            v.x = sm[r * 65 + k4 + 0];
            v.y = sm[r * 65 + k4 + 1];
            v.z = sm[r * 65 + k4 + 2];
            v.w = sm[r * 65 + k4 + 3];
            if (PART) {
                *reinterpret_cast<float4*>(
                    Tout + ((size_t)c * NB + r0 + r) * NK + k4) = v;
            } else {
                float* p = Tout + (size_t)(r0 + r) * NK + k4;
                atomicAdd(p + 0, v.x); atomicAdd(p + 1, v.y);
                atomicAdd(p + 2, v.z); atomicAdd(p + 3, v.w);
            }
        }
    }
    atomicAdd(&lin_ws[r0 + t], lin);
    atomicAdd(&dd_ws[r0 + t], dd);
}

// ---------- k_red: sum chunk partials, srow[b] = sum_k T^2 - dd[b] ----------
template <int NCH>
__global__ __launch_bounds__(256) void k_red(const float* __restrict__ Tp,
                                             const float* __restrict__ dd_ws,
                                             float* __restrict__ srow) {
    int tid = blockIdx.x * 256 + threadIdx.x;
    int row = tid >> 4;
    int k4  = (tid & 15) * 4;
    float4 s = {0.f, 0.f, 0.f, 0.f};
    for (int c = 0; c < NCH; ++c) {
        float4 p = *reinterpret_cast<const float4*>(
            Tp + ((size_t)c * NB + row) * NK + k4);
        s.x += p.x; s.y += p.y; s.z += p.z; s.w += p.w;
    }
    float v = s.x * s.x + s.y * s.y + s.z * s.z + s.w * s.w;
    #pragma unroll
    for (int m = 1; m < 16; m <<= 1) v += __shfl_xor(v, m, 64);
    if ((threadIdx.x & 15) == 0) srow[row] = v - dd_ws[row];
}

// ---------- k_final: fp64 reduce of srow + broadcast ----------
__global__ __launch_bounds__(256) void k_final(const float* __restrict__ lin_ws,
                                               const float* __restrict__ srow,
                                               const float* __restrict__ bptr,
                                               float* __restrict__ out) {
    __shared__ double red[256];
    int t = threadIdx.x;
    double a = 0.0;
    for (int j = t; j < NB; j += 256) a += (double)srow[j];
    red[t] = a;
    __syncthreads();
    #pragma unroll
    for (int s = 128; s; s >>= 1) {
        if (t < s) red[t] += red[t + s];
        __syncthreads();
    }
    float inter = (float)(0.5 * red[0]);
    float bias  = bptr[0];
    for (int j = t; j < NB; j += 256) out[j] = lin_ws[j] + bias + inter;
}

extern "C" void kernel_launch(void* const* d_in, const int* in_sizes, int n_in,
                              void* d_out, int out_size, void* d_ws, size_t ws_size,
                              hipStream_t stream) {
    const float* X    = (const float*)d_in[0];
    const float* W    = (const float*)d_in[1];
    const float* bias = (const float*)d_in[2];
    const float* vec  = (const float*)d_in[3];
    const int*   f2f  = (const int*)d_in[4];
    float* out = (float*)d_out;

    float* ws    = (float*)d_ws;
    float* Vg    = ws + WS_VG;
    float* vnorm = ws + WS_VNORM;
    float* lin   = ws + WS_LIN;
    float* dd    = ws + WS_DD;
    float* srow  = ws + WS_SROW;
    float* T     = ws + WS_T;

    const size_t need_part = ((size_t)WS_T + (size_t)NCHUNK * NB * NK) * 4;
    const bool part = ws_size >= need_part;

    // zero atomic accumulators (lin, dd are contiguous)
    hipMemsetAsync(lin, 0, 2 * NB * sizeof(float), stream);
    if (!part)
        hipMemsetAsync(T, 0, (size_t)NB * NK * sizeof(float), stream);

    k_prep<<<512, 256, 0, stream>>>(vec, f2f, Vg, vnorm);
    if (part) {
        k_main<true><<<NRG * NCHUNK, 256, 0, stream>>>(X, W, Vg, vnorm, T, lin, dd);
        k_red<NCHUNK><<<NB * 16 / 256, 256, 0, stream>>>(T, dd, srow);
    } else {
        k_main<false><<<NRG * NCHUNK, 256, 0, stream>>>(X, W, Vg, vnorm, T, lin, dd);
        k_red<1><<<NB * 16 / 256, 256, 0, stream>>>(T, dd, srow);
    }
    k_final<<<1, 256, 0, stream>>>(lin, srow, bias, out);
}